// Round 13
// baseline (199.345 us; speedup 1.0000x reference)
//
#include <hip/hip_runtime.h>
#include <hip/hip_bf16.h>

// GroupedVectorSA (gfx950) — ROUND 13: R12 structure + packed-f32 (v_pk_fma_f32)
// math in h-build / relation / output. 3 launches.

typedef __attribute__((ext_vector_type(8))) short bf16x8_t;
typedef __attribute__((ext_vector_type(4))) float f32x4_t;
typedef __attribute__((ext_vector_type(2))) float v2f;

#define BN_EPS 1e-5f
#define WSYNC() asm volatile("s_waitcnt lgkmcnt(0)" ::: "memory")

__device__ __forceinline__ float blo(unsigned int v) {
    union { unsigned int u; float f; } x; x.u = v << 16; return x.f;
}
__device__ __forceinline__ float bhi(unsigned int v) {
    union { unsigned int u; float f; } x; x.u = v & 0xffff0000u; return x.f;
}
__device__ __forceinline__ v2f upk(unsigned int v) {      // {lo, hi} as float2
    v2f r; r.x = blo(v); r.y = bhi(v); return r;
}
__device__ __forceinline__ unsigned int fbits(float f) {
    union { float f; unsigned int u; } x; x.f = f; return x.u;
}
__device__ __forceinline__ unsigned short f2b(float f) {      // RNE fp32->bf16
    unsigned int u = fbits(f);
    return (unsigned short)((u + 0x7fffu + ((u >> 16) & 1u)) >> 16);
}
__device__ __forceinline__ unsigned int f2bpk(float a, float b) {  // hw packed cvt
    union { __hip_bfloat162 h; unsigned int u; } x;
    x.h = __float22bfloat162_rn(make_float2(a, b));
    return x.u;
}
__device__ __forceinline__ unsigned int f2bpk2(v2f v) { return f2bpk(v.x, v.y); }
// relation pair, packed: r = (k-q)*pem + peb
__device__ __forceinline__ unsigned int relpair(unsigned int kb, unsigned int qb,
                                                unsigned int pm_, unsigned int pb_) {
    v2f d = upk(kb) - upk(qb);
    v2f r = __builtin_elementwise_fma(d, upk(pm_), upk(pb_));
    return f2bpk2(r);
}

// ---------------------------------------------------------------------------
// K0: blocks 0..159: 5 weights -> bf16 fragment-linear. 160: W4. 161: we1TF.
// ---------------------------------------------------------------------------
__global__ __launch_bounds__(256) void k_prep(
    const float* __restrict__ wq, const float* __restrict__ wk,
    const float* __restrict__ wv, const float* __restrict__ pm2,
    const float* __restrict__ pb2,
    const float* __restrict__ pm_w1, const float* __restrict__ pm_b1,
    const float* __restrict__ pm_bn,
    const float* __restrict__ pb_w1, const float* __restrict__ pb_b1,
    const float* __restrict__ pb_bn,
    const float* __restrict__ we_w1,
    unsigned short* __restrict__ wsT, float* __restrict__ W4,
    unsigned short* __restrict__ we1TF)
{
    const int bid = blockIdx.x, t = threadIdx.x;
    if (bid < 160) {
        __shared__ unsigned short T[32][72];
        const int mat = bid >> 5;
        const int kk  = (bid >> 2) & 7;
        const int ntq = bid & 3;
        const float* s = (mat == 0) ? wq : (mat == 1) ? wk : (mat == 2) ? wv
                         : (mat == 3) ? pm2 : pb2;
        {
            int c = t & 63, r0 = t >> 6;
            for (int i = 0; i < 8; ++i) {
                int r = r0 + i * 4;
                T[r][c] = f2b(s[(kk * 32 + r) * 256 + ntq * 64 + c]);
            }
        }
        __syncthreads();
        {
            int seg = t >> 6, lane = t & 63;
            int col = seg * 16 + (lane & 15);
            int kr  = (lane >> 4) * 8;
            unsigned int v[8];
            #pragma unroll
            for (int j = 0; j < 8; ++j) v[j] = T[kr + j][col];
            uint4 o;
            o.x = v[0] | (v[1] << 16);
            o.y = v[2] | (v[3] << 16);
            o.z = v[4] | (v[5] << 16);
            o.w = v[6] | (v[7] << 16);
            *(uint4*)(wsT + mat * 65536 + (ntq * 4 + seg) * 4096 + kk * 512 + lane * 8) = o;
        }
    } else if (bid == 160) {
        int c = t;
        float s = pm_bn[c] / sqrtf(pm_bn[768 + c] + BN_EPS);
        float4 wm = make_float4(pm_w1[c] * s, pm_w1[256 + c] * s, pm_w1[512 + c] * s,
                                (pm_b1[c] - pm_bn[512 + c]) * s + pm_bn[256 + c]);
        s = pb_bn[c] / sqrtf(pb_bn[768 + c] + BN_EPS);
        float4 wb = make_float4(pb_w1[c] * s, pb_w1[256 + c] * s, pb_w1[512 + c] * s,
                                (pb_b1[c] - pb_bn[512 + c]) * s + pb_bn[256 + c]);
        ((float4*)W4)[c]       = wm;
        ((float4*)W4)[256 + c] = wb;
    } else {
        for (int j = 0; j < 8; ++j) {
            int e = t * 8 + j;
            int g = e >> 8, c = e & 255;
            we1TF[g * 256 + c] = f2b(we_w1[c * 8 + g]);
        }
    }
}

// ---------------------------------------------------------------------------
// K1: q/k/v GEMM. grid=768, blk=256. (unchanged)
// ---------------------------------------------------------------------------
__global__ __launch_bounds__(256) void k_qkv(
    const float* __restrict__ feats,
    const unsigned short* __restrict__ wT,
    const float* __restrict__ bq, const float* __restrict__ bnq,
    const float* __restrict__ bk, const float* __restrict__ bnk,
    const float* __restrict__ bv,
    unsigned short* __restrict__ qkv)
{
    __shared__ unsigned short A[32][264];
    const int t    = threadIdx.x;
    const int widx = blockIdx.x >> 8;
    const int mb   = blockIdx.x & 255;

    for (int i = 0; i < 8; ++i) {
        int row = 4 * i + (t >> 6), col = (t & 63) * 4;
        float4 f = *(const float4*)(feats + (mb * 32 + row) * 256 + col);
        *(uint2*)&A[row][col] = make_uint2(f2bpk(f.x, f.y), f2bpk(f.z, f.w));
    }
    __syncthreads();

    const int lane = t & 63, w = t >> 6;
    const int ln15 = lane & 15, quad = lane >> 4;
    const int mt = w & 1, nh = w >> 1;

    bf16x8_t afr[8];
    #pragma unroll
    for (int kk = 0; kk < 8; ++kk)
        afr[kk] = *(const bf16x8_t*)&A[mt * 16 + ln15][kk * 32 + quad * 8];

    const unsigned short* W = wT + widx * 65536;
    const float* bias = (widx == 0) ? bq : (widx == 1) ? bk : bv;
    const float* bn   = (widx == 0) ? bnq : (widx == 1) ? bnk : nullptr;
    unsigned short* dst = qkv + (size_t)widx * 8192 * 256;

    f32x4_t acc[8];
    for (int j = 0; j < 8; ++j) acc[j] = (f32x4_t){0.f, 0.f, 0.f, 0.f};

    #pragma unroll
    for (int kk = 0; kk < 8; ++kk) {
        #pragma unroll
        for (int j = 0; j < 8; ++j) {
            int nt = nh * 8 + j;
            bf16x8_t bfr = *(const bf16x8_t*)(W + ((nt * 8 + kk) * 64 + lane) * 8);
            acc[j] = __builtin_amdgcn_mfma_f32_16x16x32_bf16(afr[kk], bfr, acc[j], 0, 0, 0);
        }
    }

    float bb[8], sc[8], mu[8], be[8];
    #pragma unroll
    for (int j = 0; j < 8; ++j) {
        int c = (nh * 8 + j) * 16 + ln15;
        bb[j] = bias[c];
        if (bn) {
            sc[j] = bn[c] / sqrtf(bn[768 + c] + BN_EPS);
            be[j] = bn[256 + c];
            mu[j] = bn[512 + c];
        }
    }
    __syncthreads();
    #pragma unroll
    for (int j = 0; j < 8; ++j) {
        int c = (nh * 8 + j) * 16 + ln15;
        float y[4];
        for (int r = 0; r < 4; ++r) {
            y[r] = acc[j][r] + bb[j];
            if (bn) y[r] = fmaxf((y[r] - mu[j]) * sc[j] + be[j], 0.f);
        }
        for (int r = 0; r < 4; r += 2) {
            unsigned int pk = f2bpk(y[r], y[r + 1]);
            A[mt * 16 + quad * 4 + r][c]     = (unsigned short)pk;
            A[mt * 16 + quad * 4 + r + 1][c] = (unsigned short)(pk >> 16);
        }
    }
    __syncthreads();
    {
        int row = t >> 3, cc = (t & 7) * 32;
        #pragma unroll
        for (int j = 0; j < 4; ++j) {
            uint4 v = *(const uint4*)&A[row][cc + 8 * j];
            *(uint4*)(dst + (mb * 32 + row) * 256 + cc + 8 * j) = v;
        }
    }
}

// ---------------------------------------------------------------------------
// K2: fused main. 512 threads (8 waves), 4 points/block, wave pair per point.
// ---------------------------------------------------------------------------
__global__ __launch_bounds__(512, 4) void k_main(
    const float* __restrict__ coords,
    const int*   __restrict__ index,
    const unsigned short* __restrict__ qm,
    const unsigned short* __restrict__ km,
    const unsigned short* __restrict__ vm,
    const unsigned short* __restrict__ pmw2F,
    const unsigned short* __restrict__ pbw2F,
    const float* __restrict__ W4,
    const unsigned short* __restrict__ we1TF,
    const float* __restrict__ pm_b2, const float* __restrict__ pb_b2,
    const float* __restrict__ we_b1, const float* __restrict__ we_bn,
    const float* __restrict__ we_w2, const float* __restrict__ we_b2,
    float* __restrict__ out)
{
    __shared__ unsigned short bufR[64][264];   // h0 -> h1 -> pem
    __shared__ unsigned short bufP[64][264];   // peb
    __shared__ float posA[64][4];
    __shared__ float usP[2][64][8];            // partial logits (K-split halves)
    __shared__ float us_[64][8];               // logits -> softmax w
    __shared__ int   rowg_[64];
    __shared__ float we2s[8][8];
    __shared__ float web2[8], swe8[8], dwe8[8];

    const int t   = threadIdx.x;
    const int P0  = blockIdx.x * 4;
    const int bb_ = P0 >> 12;
    const int w = t >> 6, lane = t & 63;
    const int ln15 = lane & 15, quad = lane >> 4;
    const int p   = w >> 1, sub = w & 1;
    const int R0  = p * 16;
    const int Pg  = P0 + p;

    // ---- per-lane neighbor row (s=ln15) + k prefetch, K-half sub ----
    const int rg = (bb_ << 12) + index[Pg * 16 + ln15];
    uint4 kpre[4];
    #pragma unroll
    for (int kk = 0; kk < 4; ++kk)
        kpre[kk] = *(const uint4*)(km + rg * 256 + (sub * 4 + kk) * 32 + quad * 8);

    // ---- per-wave pos/rowg staging: own 8 rows (lanes<8) ----
    if (lane < 8) {
        int m  = w * 8 + lane;
        int Pr = P0 + (m >> 4);
        int rs = (bb_ << 12) + index[Pr * 16 + (m & 15)];
        rowg_[m]   = rs;
        posA[m][0] = coords[Pr * 3 + 0] - coords[rs * 3 + 0];
        posA[m][1] = coords[Pr * 3 + 1] - coords[rs * 3 + 1];
        posA[m][2] = coords[Pr * 3 + 2] - coords[rs * 3 + 2];
        posA[m][3] = 0.f;
    }
    if (t < 64) we2s[t >> 3][t & 7] = we_w2[t];
    if (t < 8) {
        float s = we_bn[t] / sqrtf(we_bn[24 + t] + BN_EPS);
        swe8[t] = s;
        dwe8[t] = (we_b1[t] - we_bn[16 + t]) * s + we_bn[8 + t];
        web2[t] = we_b2[t];
    }
    WSYNC();

    const int hc = lane * 4;                   // 4 cols per lane (2 v2f pairs)
    const int hm = w * 8;                      // 8 rows per wave

    // packed layer-1 coeff vectors for this lane's 2 col-pairs
    v2f w0a, w1a, w2a, w3a, w0b, w1b, w2b, w3b;     // pm (pass1)
    v2f x0a, x1a, x2a, x3a, x0b, x1b, x2b, x3b;     // pb (pass0)
    {
        float4 A0 = ((const float4*)W4)[hc],     A1 = ((const float4*)W4)[hc + 1];
        float4 A2 = ((const float4*)W4)[hc + 2], A3 = ((const float4*)W4)[hc + 3];
        w0a = (v2f){A0.x, A1.x}; w1a = (v2f){A0.y, A1.y};
        w2a = (v2f){A0.z, A1.z}; w3a = (v2f){A0.w, A1.w};
        w0b = (v2f){A2.x, A3.x}; w1b = (v2f){A2.y, A3.y};
        w2b = (v2f){A2.z, A3.z}; w3b = (v2f){A2.w, A3.w};
        float4 B0 = ((const float4*)W4)[256 + hc],     B1 = ((const float4*)W4)[256 + hc + 1];
        float4 B2 = ((const float4*)W4)[256 + hc + 2], B3 = ((const float4*)W4)[256 + hc + 3];
        x0a = (v2f){B0.x, B1.x}; x1a = (v2f){B0.y, B1.y};
        x2a = (v2f){B0.z, B1.z}; x3a = (v2f){B0.w, B1.w};
        x0b = (v2f){B2.x, B3.x}; x1b = (v2f){B2.y, B3.y};
        x2b = (v2f){B2.z, B3.z}; x3b = (v2f){B2.w, B3.w};
    }
    const v2f vz = {0.f, 0.f};

    // ---- h0 (pb hidden) -> bufR: packed fma chain ----
    #pragma unroll
    for (int m = 0; m < 8; ++m) {
        float4 pp = *(const float4*)&posA[hm + m][0];
        v2f px = (v2f){pp.x, pp.x}, py = (v2f){pp.y, pp.y}, pz = (v2f){pp.z, pp.z};
        v2f ha = __builtin_elementwise_fma(px, x0a,
                 __builtin_elementwise_fma(py, x1a,
                 __builtin_elementwise_fma(pz, x2a, x3a)));
        v2f hb = __builtin_elementwise_fma(px, x0b,
                 __builtin_elementwise_fma(py, x1b,
                 __builtin_elementwise_fma(pz, x2b, x3b)));
        ha = __builtin_elementwise_max(ha, vz);
        hb = __builtin_elementwise_max(hb, vz);
        *(uint2*)&bufR[hm + m][hc] = make_uint2(f2bpk2(ha), f2bpk2(hb));
    }
    __syncthreads();                           // B1

    // ---- pass0 MFMA: peb. wave N-band nt = w*2..w*2+1, acc init = bias ----
    f32x4_t acc[2][4];
    {
        float b0 = pb_b2[(w * 2    ) * 16 + ln15];
        float b1 = pb_b2[(w * 2 + 1) * 16 + ln15];
        for (int mt = 0; mt < 4; ++mt) {
            acc[0][mt] = (f32x4_t){b0, b0, b0, b0};
            acc[1][mt] = (f32x4_t){b1, b1, b1, b1};
        }
    }
    #pragma unroll
    for (int kk = 0; kk < 8; ++kk) {
        bf16x8_t afr[4];
        #pragma unroll
        for (int mt = 0; mt < 4; ++mt)
            afr[mt] = *(const bf16x8_t*)&bufR[mt * 16 + ln15][kk * 32 + quad * 8];
        #pragma unroll
        for (int ntl = 0; ntl < 2; ++ntl) {
            int nt = w * 2 + ntl;
            bf16x8_t bfr = *(const bf16x8_t*)(pbw2F + ((nt * 8 + kk) * 64 + lane) * 8);
            #pragma unroll
            for (int mt = 0; mt < 4; ++mt)
                acc[ntl][mt] = __builtin_amdgcn_mfma_f32_16x16x32_bf16(afr[mt], bfr, acc[ntl][mt], 0, 0, 0);
        }
    }
    __syncthreads();                           // B2

    // peb epilogue -> bufP
    #pragma unroll
    for (int ntl = 0; ntl < 2; ++ntl) {
        int c = (w * 2 + ntl) * 16 + ln15;
        for (int mt = 0; mt < 4; ++mt)
            for (int r = 0; r < 4; r += 2) {
                unsigned int pk = f2bpk(acc[ntl][mt][r], acc[ntl][mt][r + 1]);
                bufP[mt * 16 + quad * 4 + r][c]     = (unsigned short)pk;
                bufP[mt * 16 + quad * 4 + r + 1][c] = (unsigned short)(pk >> 16);
            }
    }
    // h1 (pm hidden) -> bufR
    #pragma unroll
    for (int m = 0; m < 8; ++m) {
        float4 pp = *(const float4*)&posA[hm + m][0];
        v2f px = (v2f){pp.x, pp.x}, py = (v2f){pp.y, pp.y}, pz = (v2f){pp.z, pp.z};
        v2f ha = __builtin_elementwise_fma(px, w0a,
                 __builtin_elementwise_fma(py, w1a,
                 __builtin_elementwise_fma(pz, w2a, w3a)));
        v2f hb = __builtin_elementwise_fma(px, w0b,
                 __builtin_elementwise_fma(py, w1b,
                 __builtin_elementwise_fma(pz, w2b, w3b)));
        ha = __builtin_elementwise_max(ha, vz);
        hb = __builtin_elementwise_max(hb, vz);
        *(uint2*)&bufR[hm + m][hc] = make_uint2(f2bpk2(ha), f2bpk2(hb));
    }
    __syncthreads();                           // B3

    // ---- pass1 MFMA: pem, acc init = bias ----
    {
        float b0 = pm_b2[(w * 2    ) * 16 + ln15];
        float b1 = pm_b2[(w * 2 + 1) * 16 + ln15];
        for (int mt = 0; mt < 4; ++mt) {
            acc[0][mt] = (f32x4_t){b0, b0, b0, b0};
            acc[1][mt] = (f32x4_t){b1, b1, b1, b1};
        }
    }
    #pragma unroll
    for (int kk = 0; kk < 8; ++kk) {
        bf16x8_t afr[4];
        #pragma unroll
        for (int mt = 0; mt < 4; ++mt)
            afr[mt] = *(const bf16x8_t*)&bufR[mt * 16 + ln15][kk * 32 + quad * 8];
        #pragma unroll
        for (int ntl = 0; ntl < 2; ++ntl) {
            int nt = w * 2 + ntl;
            bf16x8_t bfr = *(const bf16x8_t*)(pmw2F + ((nt * 8 + kk) * 64 + lane) * 8);
            #pragma unroll
            for (int mt = 0; mt < 4; ++mt)
                acc[ntl][mt] = __builtin_amdgcn_mfma_f32_16x16x32_bf16(afr[mt], bfr, acc[ntl][mt], 0, 0, 0);
        }
    }
    __syncthreads();                           // B4

    // pem epilogue -> bufR
    #pragma unroll
    for (int ntl = 0; ntl < 2; ++ntl) {
        int c = (w * 2 + ntl) * 16 + ln15;
        for (int mt = 0; mt < 4; ++mt)
            for (int r = 0; r < 4; r += 2) {
                unsigned int pk = f2bpk(acc[ntl][mt][r], acc[ntl][mt][r + 1]);
                bufR[mt * 16 + quad * 4 + r][c]     = (unsigned short)pk;
                bufR[mt * 16 + quad * 4 + r + 1][c] = (unsigned short)(pk >> 16);
            }
    }
    __syncthreads();                           // B5

    // ---- relation + partial logits (K-half = sub), packed math ----
    {
        const bf16x8_t bz = {0, 0, 0, 0, 0, 0, 0, 0};
        f32x4_t lacc = {0.f, 0.f, 0.f, 0.f};
        #pragma unroll
        for (int kk = 0; kk < 4; ++kk) {
            int cb8 = (sub * 4 + kk) * 32 + quad * 8;
            uint4 pm4 = *(const uint4*)&bufR[R0 + ln15][cb8];
            uint4 pb4 = *(const uint4*)&bufP[R0 + ln15][cb8];
            uint4 q4  = *(const uint4*)(qm + Pg * 256 + cb8);
            union { uint4 u; bf16x8_t v; } rr;
            rr.u.x = relpair(kpre[kk].x, q4.x, pm4.x, pb4.x);
            rr.u.y = relpair(kpre[kk].y, q4.y, pm4.y, pb4.y);
            rr.u.z = relpair(kpre[kk].z, q4.z, pm4.z, pb4.z);
            rr.u.w = relpair(kpre[kk].w, q4.w, pm4.w, pb4.w);
            bf16x8_t bfr = bz;
            if (ln15 < 8) bfr = *(const bf16x8_t*)(we1TF + ln15 * 256 + cb8);
            lacc = __builtin_amdgcn_mfma_f32_16x16x32_bf16(rr.v, bfr, lacc, 0, 0, 0);
        }
        if (ln15 < 8) {
            #pragma unroll
            for (int r = 0; r < 4; ++r)
                usP[sub][R0 + quad * 4 + r][ln15] = lacc[r];
        }
    }
    __syncthreads();                           // B6

    // ---- combine + BN/relu + logits2 (even wave, lanes<16 = s) ----
    if (sub == 0 && lane < 16) {
        int s = lane;
        float uv[8], l[8];
        #pragma unroll
        for (int g = 0; g < 8; ++g) {
            float x = usP[0][R0 + s][g] + usP[1][R0 + s][g];
            uv[g] = fmaxf(x * swe8[g] + dwe8[g], 0.f);
        }
        #pragma unroll
        for (int g = 0; g < 8; ++g) {
            float x = web2[g];
            for (int gp = 0; gp < 8; ++gp) x += uv[gp] * we2s[gp][g];
            l[g] = x;
        }
        #pragma unroll
        for (int g = 0; g < 8; ++g) us_[R0 + s][g] = l[g];
    }
    WSYNC();

    // ---- softmax over s (even wave, lanes<8 = g) ----
    if (sub == 0 && lane < 8) {
        int g = lane;
        float mx = -1e30f;
        for (int s = 0; s < 16; ++s) mx = fmaxf(mx, us_[R0 + s][g]);
        float e[16], sum = 0.f;
        for (int s = 0; s < 16; ++s) { e[s] = __expf(us_[R0 + s][g] - mx); sum += e[s]; }
        float inv = 1.f / sum;
        for (int s = 0; s < 16; ++s) us_[R0 + s][g] = e[s] * inv;
    }
    __syncthreads();                           // B7

    // ---- output: wave pair = 128 lanes, 2 cols each, packed accumulate ----
    {
        int idx2 = sub * 64 + lane;
        int c5 = idx2 * 2, g = c5 >> 5;
        v2f a = {0.f, 0.f};
        #pragma unroll
        for (int s = 0; s < 16; ++s) {
            int rv = rowg_[R0 + s];
            float wv_ = us_[R0 + s][g];
            unsigned int v2 = *(const unsigned int*)(vm + rv * 256 + c5);
            unsigned int p2 = *(const unsigned int*)&bufP[R0 + s][c5];
            v2f ws = (v2f){wv_, wv_};
            a = __builtin_elementwise_fma(ws, upk(v2) + upk(p2), a);
        }
        *(float2*)(out + (size_t)Pg * 256 + c5) = make_float2(a.x, a.y);
    }
}

// ---------------------------------------------------------------------------
extern "C" void kernel_launch(void* const* d_in, const int* in_sizes, int n_in,
                              void* d_out, int out_size, void* d_ws, size_t ws_size,
                              hipStream_t stream)
{
    const float* feats  = (const float*)d_in[0];
    const float* coords = (const float*)d_in[1];
    const int*   index  = (const int*)d_in[2];
    const float* wq     = (const float*)d_in[3];
    const float* bq     = (const float*)d_in[4];
    const float* bnq    = (const float*)d_in[5];
    const float* wk     = (const float*)d_in[6];
    const float* bk     = (const float*)d_in[7];
    const float* bnk    = (const float*)d_in[8];
    const float* wv     = (const float*)d_in[9];
    const float* bv     = (const float*)d_in[10];
    const float* pm_w1  = (const float*)d_in[11];
    const float* pm_b1  = (const float*)d_in[12];
    const float* pm_bn  = (const float*)d_in[13];
    const float* pm_w2  = (const float*)d_in[14];
    const float* pm_b2  = (const float*)d_in[15];
    const float* pb_w1  = (const float*)d_in[16];
    const float* pb_b1  = (const float*)d_in[17];
    const float* pb_bn  = (const float*)d_in[18];
    const float* pb_w2  = (const float*)d_in[19];
    const float* pb_b2  = (const float*)d_in[20];
    const float* we_w1  = (const float*)d_in[21];
    const float* we_b1  = (const float*)d_in[22];
    const float* we_bn  = (const float*)d_in[23];
    const float* we_w2  = (const float*)d_in[24];
    const float* we_b2  = (const float*)d_in[25];

    unsigned short* qkv   = (unsigned short*)d_ws;
    unsigned short* wsT   = qkv + (size_t)3 * 8192 * 256;
    float*          W4    = (float*)(wsT + 5 * 65536);
    unsigned short* we1TF = (unsigned short*)(W4 + 2048);

    const size_t need = (size_t)13238272 + 8192 + 4096;
    if (ws_size < need) {
        hipMemsetAsync(d_out, 0, (size_t)out_size * 4, stream);
        return;
    }

    k_prep<<<162,  256, 0, stream>>>(wq, wk, wv, pm_w2, pb_w2,
                                     pm_w1, pm_b1, pm_bn,
                                     pb_w1, pb_b1, pb_bn,
                                     we_w1, wsT, W4, we1TF);
    k_qkv <<<768,  256, 0, stream>>>(feats, wsT, bq, bnq, bk, bnk, bv, qkv);
    k_main<<<2048, 512, 0, stream>>>(coords, index,
                                     qkv,
                                     qkv + (size_t)8192 * 256,
                                     qkv + (size_t)2 * 8192 * 256,
                                     wsT + 3 * 65536,
                                     wsT + 4 * 65536,
                                     W4, we1TF,
                                     pm_b2, pb_b2,
                                     we_b1, we_bn, we_w2, we_b2,
                                     (float*)d_out);
}